// Round 11
// baseline (3064.535 us; speedup 1.0000x reference)
//
#include <hip/hip_runtime.h>

// ---------------------------------------------------------------------------
// PointNet++ (defense variant) forward on MI355X.
// B=8, N=4096 -> 2048 -> 512, K=32 neighbors. Geometry is EXACT: positions are
// multiples of 2^-23 (f64 knn d2 / i64 fps d2 are exact) — discrete choices
// match an np-f64 reference exactly.
// R11: FPS cross-wave reduce via ONE LDS u64 atomicMax slot (3-slot ring,
// reset one-window-ahead; barriers order the windows). Cuts per-iter LDS ops
// per wave 6 -> 3 and removes the 8-partial read+tree from the serial chain
// (R7 vs R10 proved per-iter is invariant to wave count/update size ->
// LDS-pipe + dependent-read latency is the binding term).
// ---------------------------------------------------------------------------

#define NB 8

__device__ __forceinline__ unsigned obits(float f) {
  unsigned u = __float_as_uint(f);
  return (u & 0x80000000u) ? ~u : (u | 0x80000000u);
}

static constexpr int CAND = 1024;

// ---------------- DPP helpers (VALU cross-lane, no LDS pipe) ----------------
template<int CTRL>
__device__ __forceinline__ unsigned long long dpp_max_step(unsigned long long v) {
  const int lo = (int)(unsigned)(v & 0xffffffffull);
  const int hi = (int)(unsigned)(v >> 32);
  const unsigned nlo = (unsigned)__builtin_amdgcn_update_dpp(lo, lo, CTRL, 0xf, 0xf, false);
  const unsigned nhi = (unsigned)__builtin_amdgcn_update_dpp(hi, hi, CTRL, 0xf, 0xf, false);
  const unsigned long long nv = ((unsigned long long)nhi << 32) | nlo;
  return (nv > v) ? nv : v;
}

// wave64 inclusive prefix-sum (gfx9 DPP idiom; correctness-verified R9)
__device__ __forceinline__ unsigned wave_iscan_add(unsigned x) {
  x += (unsigned)__builtin_amdgcn_update_dpp(0, (int)x, 0x111, 0xf, 0xf, true); // shr1
  x += (unsigned)__builtin_amdgcn_update_dpp(0, (int)x, 0x112, 0xf, 0xf, true); // shr2
  x += (unsigned)__builtin_amdgcn_update_dpp(0, (int)x, 0x114, 0xf, 0xf, true); // shr4
  x += (unsigned)__builtin_amdgcn_update_dpp(0, (int)x, 0x118, 0xf, 0xf, true); // shr8
  x += (unsigned)__builtin_amdgcn_update_dpp(0, (int)x, 0x142, 0xa, 0xf, true); // bcast15
  x += (unsigned)__builtin_amdgcn_update_dpp(0, (int)x, 0x143, 0xc, 0xf, true); // bcast31
  return x;
}

// ---------------- FPS body (exact integer keys, deterministic) --------------
// key = (d2 << 12) | (4095 - j)  =>  max key == (max d2, tie -> min j).
// Cross-wave reduce: lane 63 of each wave atomicMax's into slot[t%3];
// tid0 resets slot[(t+1)%3] pre-barrier (its readers finished 2 barriers ago);
// post-barrier every thread reads the single winner key (b64 broadcast).
template<int N, int NOUT, int T>
__device__ __forceinline__ void fps_body(char* sm, const float* __restrict__ pb,
                                         int* __restrict__ fi, int b) {
  constexpr int P = N / T;
  int4* sPosI = (int4*)sm;                                   // [N]
  int*  sfi   = (int*)(sm + (size_t)N * 16);                 // [NOUT]
  unsigned long long* slot =
      (unsigned long long*)(sm + (size_t)N * 16 + NOUT * 4); // [3]
  const int tid = threadIdx.x, lane = tid & 63;
  int ix[P], iy[P], iz[P];
  unsigned long long mind[P];
  for (int t = tid; t < N; t += T) {
    sPosI[t] = make_int4((int)(pb[3*t]   * 8388608.f),   // exact: 2^-23 multiples
                         (int)(pb[3*t+1] * 8388608.f),
                         (int)(pb[3*t+2] * 8388608.f), 0);
  }
  if (tid < 3) slot[tid] = 0ull;
  __syncthreads();
  const int x0 = sPosI[0].x, y0 = sPosI[0].y, z0 = sPosI[0].z;
  const int invBase = 4095 - tid * P;
  unsigned long long bv;
  {
    unsigned long long tv[P];
#pragma unroll
    for (int e = 0; e < P; e++) {
      const int j = tid * P + e;
      const int4 p4 = sPosI[j];
      ix[e] = p4.x; iy[e] = p4.y; iz[e] = p4.z;
      const long long dx = p4.x - x0, dy = p4.y - y0, dz = p4.z - z0;
      const unsigned long long d2 =
          (unsigned long long)(dx * dx + dy * dy + dz * dz);   // exact, < 2^48
      const unsigned long long k = (d2 << 12) | (unsigned)(invBase - e);
      mind[e] = k; tv[e] = k;
    }
#pragma unroll
    for (int s = 1; s < P; s <<= 1)
#pragma unroll
      for (int e = 0; e + s < P; e += 2 * s)
        if (tv[e + s] > tv[e]) tv[e] = tv[e + s];
    bv = tv[0];
  }
  if (tid == 0) sfi[0] = 0;
  int sl = 1;                      // t % 3, maintained incrementally
  for (int t = 1; t < NOUT; t++) {
    unsigned long long v = bv;
    v = dpp_max_step<0x111>(v);   // row_shr:1
    v = dpp_max_step<0x112>(v);   // row_shr:2
    v = dpp_max_step<0x114>(v);   // row_shr:4
    v = dpp_max_step<0x118>(v);   // row_shr:8
    v = dpp_max_step<0x142>(v);   // row_bcast:15
    v = dpp_max_step<0x143>(v);   // row_bcast:31
    if (lane == 63) atomicMax(&slot[sl], v);          // wave winner -> one slot
    const int nx = (sl == 2) ? 0 : sl + 1;
    if (tid == 0) slot[nx] = 0ull;                    // reset one window ahead
    __syncthreads();   // orders atomics/reset across windows; drains LDS only
    const unsigned long long best = slot[sl];         // b64 same-addr broadcast
    sl = nx;
    const int ii = 4095 - (int)(best & 0xFFFull);
    if (tid == 0) sfi[t] = ii;
    const int4 wc = sPosI[ii];                        // b128 same-addr broadcast
    unsigned long long tv[P];
#pragma unroll
    for (int e = 0; e < P; e++) {
      const long long dx = ix[e] - wc.x, dy = iy[e] - wc.y, dz = iz[e] - wc.z;
      const unsigned long long nd =
          (unsigned long long)(dx * dx + dy * dy + dz * dz);
      const unsigned long long nk = (nd << 12) | (unsigned)(invBase - e);
      unsigned long long mk = mind[e];
      mk = (nk < mk) ? nk : mk;
      mind[e] = mk;
      tv[e] = mk;
    }
#pragma unroll
    for (int s = 1; s < P; s <<= 1)
#pragma unroll
      for (int e = 0; e + s < P; e += 2 * s)
        if (tv[e + s] > tv[e]) tv[e] = tv[e + s];
    bv = tv[0];
  }
  __syncthreads();
  for (int t = tid; t < NOUT; t += T) fi[(size_t)b * NOUT + t] = sfi[t];
}

// ---------------- knn (exact f64 top-32, LDS d2s) + conv fused per row ------
template<int N, int H, int C, bool HASX, int T>
__device__ __forceinline__ void knnconv_body(
    char* sm, const float* __restrict__ pb, int b, int i,
    const float* __restrict__ U, const float* __restrict__ Wrel,
    const float* __restrict__ b1, const float* __restrict__ W2,
    const float* __restrict__ b2, float* __restrict__ out, double rr) {
  constexpr int HCHUNK = (C == 64) ? 64 : (C == 128 ? 32 : 16);
  constexpr int STR = HCHUNK + 4;
  constexpr int NW = T / 64;        // k-groups
  constexpr int EPK = 32 / NW;      // k's per thread
  constexpr int BPT = 2048 / T;     // histogram bins per thread
  constexpr int KNNFRONT = N * 8 + 13312;
  constexpr int CONVFRONT = 32 * H * 4 + C * STR * 4 + NW * C * 4;
  constexpr int FRONT = (KNNFRONT > CONVFRONT) ? KNNFRONT : CONVFRONT;
  // knn views
  double*   d2s     = (double*)sm;                        // [N]
  unsigned* hist    = (unsigned*)(sm + N * 8);            // [2048]
  int*      candIdx = (int*)(sm + N * 8 + 8192);          // [CAND]
  unsigned* sWT     = (unsigned*)(sm + N * 8 + 12288);    // [NW]
  // conv views (alias the knn front; born after ranking completes)
  float* h1s  = (float*)sm;                               // [32*H]
  float* sW2T = (float*)(sm + 32 * H * 4);                // [C*STR]
  float* sRed = (float*)(sm + 32 * H * 4 + C * STR * 4);  // [NW][C]
  // tail (never aliased)
  int*   snbr = (int*)(sm + FRONT);                       // [32]
  float* rel  = (float*)(sm + FRONT + 128);               // [32][3]
  int*   pcnt = (int*)(sm + FRONT + 128 + 384);
  int*   pbin = pcnt + 1;
  const int tid = threadIdx.x;

  // --- distance pass: exact f64 d2 into LDS ---
  const double xi = pb[3*i], yi = pb[3*i+1], zi = pb[3*i+2];
  const double si = (xi*xi + yi*yi) + zi*zi;
  for (int t = tid; t < 2048; t += T) hist[t] = 0u;
  if (tid == 0) *pcnt = 0;
  __syncthreads();
  for (int j = tid; j < N; j += T) {
    double xj = pb[3*j], yj = pb[3*j+1], zj = pb[3*j+2];
    double sj = (xj*xj + yj*yj) + zj*zj;
    double dt = (xi*xj + yi*yj) + zi*zj;
    double d2 = (si + sj) - 2.0*dt;       // exact in f64
    if (j == i) d2 += 1e9;                // self-exclusion
    d2s[j] = d2;
    atomicAdd(&hist[obits((float)d2) >> 21], 1u);
  }
  __syncthreads();
  // --- bin threshold via DPP scan ---
  unsigned lsum = 0;
  const int base = tid * BPT;
#pragma unroll
  for (int q = 0; q < BPT; q++) lsum += hist[base + q];
  const unsigned isc = wave_iscan_add(lsum);
  if ((tid & 63) == 63) sWT[tid >> 6] = isc;
  __syncthreads();
  {
    const int wid = tid >> 6;
    unsigned offs = 0;
#pragma unroll
    for (int w2 = 0; w2 < NW; w2++) offs += (w2 < wid) ? sWT[w2] : 0u;
    const unsigned incl = isc + offs, excl = incl - lsum;
    if (excl < 32u && incl >= 32u) {
      unsigned c = excl;
      for (int q = 0; q < BPT; q++) {
        c += hist[base + q];
        if (c >= 32u) { *pbin = base + q; break; }
      }
    }
  }
  __syncthreads();
  const int binT = *pbin;
  for (int j = tid; j < N; j += T) {
    if ((int)(obits((float)d2s[j]) >> 21) <= binT) {
      int p = atomicAdd(pcnt, 1);
      if (p < CAND) candIdx[p] = j;
    }
  }
  __syncthreads();
  const int M = min(*pcnt, CAND);   // true top-32 superset (proxy monotone)
  for (int c = tid; c < M; c += T) {
    const int j = candIdx[c];
    const double d = d2s[j];
    int rank = 0;
    for (int e = 0; e < M; e++) {
      const int j2 = candIdx[e];
      const double de = d2s[j2];
      rank += (de < d || (de == d && j2 < j)) ? 1 : 0;
    }
    if (rank < 32) snbr[rank] = (d <= rr) ? j : -1;
  }
  __syncthreads();                 // knn LDS dead from here; snbr valid

  // --- rel ---
  if (tid < 32) {
    const int j = snbr[tid];
    float rx = 0.f, ry = 0.f, rz = 0.f;
    if (j >= 0) {
      rx = pb[3*j]   - pb[3*i];
      ry = pb[3*j+1] - pb[3*i+1];
      rz = pb[3*j+2] - pb[3*i+2];
    }
    rel[tid*3+0] = rx; rel[tid*3+1] = ry; rel[tid*3+2] = rz;
  }
  __syncthreads();

  // --- conv phase B: h1[k][h0..h0+3] = relu(U[j] (+b1) + rel . Wrel) ---
  constexpr int QPK = H / 4;
  for (int qi = tid; qi < 32 * QPK; qi += T) {
    const int k = qi / QPK, h0 = (qi - k * QPK) * 4;
    const int j = snbr[k];
    float4 v = make_float4(0.f, 0.f, 0.f, 0.f);
    if (j >= 0) {
      float4 a = HASX ? *(const float4*)&U[((size_t)b * N + j) * H + h0]
                      : *(const float4*)&b1[h0];
      const float rx = rel[k*3], ry = rel[k*3+1], rz = rel[k*3+2];
      const float4 w0 = *(const float4*)&Wrel[h0];
      const float4 w1 = *(const float4*)&Wrel[H + h0];
      const float4 w2 = *(const float4*)&Wrel[2 * H + h0];
      a.x += rx * w0.x + ry * w1.x + rz * w2.x;
      a.y += rx * w0.y + ry * w1.y + rz * w2.y;
      a.z += rx * w0.z + ry * w1.z + rz * w2.z;
      a.w += rx * w0.w + ry * w1.w + rz * w2.w;
      v = make_float4(fmaxf(a.x, 0.f), fmaxf(a.y, 0.f),
                      fmaxf(a.z, 0.f), fmaxf(a.w, 0.f));
    }
    *(float4*)&h1s[k * H + h0] = v;
  }
  const int cc = tid & 63;
  const int kk = tid >> 6;          // 0..NW-1
  constexpr int CC = C / 64;
  float acc[EPK][CC];
#pragma unroll
  for (int e = 0; e < EPK; e++)
#pragma unroll
    for (int q = 0; q < CC; q++) acc[e][q] = 0.f;
  // --- conv phase C: h2 = h1 @ W2 (W2 staged transposed+padded) ---
  for (int hc = 0; hc < H; hc += HCHUNK) {
    __syncthreads();
    for (int idx = tid; idx < HCHUNK * C; idx += T) {
      const int hh = idx / C, c = idx - hh * C;
      sW2T[c * STR + hh] = W2[(size_t)(hc + hh) * C + c];
    }
    __syncthreads();
    for (int hh0 = 0; hh0 < HCHUNK; hh0 += 4) {
      float4 wv[CC];
#pragma unroll
      for (int q = 0; q < CC; q++)
        wv[q] = *(const float4*)&sW2T[(cc + q * 64) * STR + hh0];
#pragma unroll
      for (int e = 0; e < EPK; e++) {
        const float4 hv = *(const float4*)&h1s[(kk + e * NW) * H + hc + hh0];
#pragma unroll
        for (int q = 0; q < CC; q++) {
          acc[e][q] += hv.x * wv[q].x;
          acc[e][q] += hv.y * wv[q].y;
          acc[e][q] += hv.z * wv[q].z;
          acc[e][q] += hv.w * wv[q].w;
        }
      }
    }
  }
  // --- masked max over k, +b2, relu ---
  float m[CC];
#pragma unroll
  for (int q = 0; q < CC; q++) m[q] = -1e9f;
#pragma unroll
  for (int e = 0; e < EPK; e++) {
    if (snbr[kk + e * NW] >= 0) {
#pragma unroll
      for (int q = 0; q < CC; q++) m[q] = fmaxf(m[q], acc[e][q]);
    }
  }
#pragma unroll
  for (int q = 0; q < CC; q++) sRed[kk * C + cc + q * 64] = m[q];
  __syncthreads();
  if (kk == 0) {
#pragma unroll
    for (int q = 0; q < CC; q++) {
      const int c = cc + q * 64;
      float mm = sRed[c];
#pragma unroll
      for (int w2 = 1; w2 < NW; w2++) mm = fmaxf(mm, sRed[w2 * C + c]);
      const float o = (mm > -5e8f) ? (mm + b2[c]) : -1e9f;
      out[((size_t)b * N + i) * C + c] = fmaxf(o, 0.f);
    }
  }
}

// ---------------- fused stage: blocks 0..NB-1 = FPS, rest = knn+conv --------
template<int N, int NOUT, int H, int C, bool HASX, int SMSIZE>
__global__ __attribute__((amdgpu_waves_per_eu(2, 2))) __launch_bounds__(512, 2)
void stage_fused(const float* __restrict__ pos, double rr, int* __restrict__ fi,
                 const float* __restrict__ U, const float* __restrict__ Wrel,
                 const float* __restrict__ b1, const float* __restrict__ W2,
                 const float* __restrict__ b2, float* __restrict__ out) {
  __shared__ __align__(16) char sm[SMSIZE];
  if (blockIdx.x < NB) {
    fps_body<N, NOUT, 512>(sm, pos + (size_t)blockIdx.x * N * 3, fi, blockIdx.x);
  } else {
    const int row = blockIdx.x - NB;
    const int b = row / N;
    const int i = row - b * N;
    knnconv_body<N, H, C, HASX, 512>(sm, pos + (size_t)b * N * 3, b, i,
                                     U, Wrel, b1, W2, b2, out, rr);
  }
}

// ---------------- stage 3: knn+conv only (256 threads, R8-proven) -----------
template<int N, int H, int C, bool HASX, int SMSIZE>
__global__ __launch_bounds__(256)
void stage_plain(const float* __restrict__ pos, double rr,
                 const float* __restrict__ U, const float* __restrict__ Wrel,
                 const float* __restrict__ b1, const float* __restrict__ W2,
                 const float* __restrict__ b2, float* __restrict__ out) {
  __shared__ __align__(16) char sm[SMSIZE];
  const int b = blockIdx.x / N;
  const int i = blockIdx.x - b * N;
  knnconv_body<N, H, C, HASX, 256>(sm, pos + (size_t)b * N * 3, b, i,
                                   U, Wrel, b1, W2, b2, out, rr);
}

// ---------------- fused gather + preproj (U = x[fi] @ W[:CIN] + b) ----------
template<int CIN, int HH>
__global__ __launch_bounds__(HH)
void gp_kernel(const float* __restrict__ X, const float* __restrict__ posPrev,
               const int* __restrict__ fi, int Nprev, int M,
               const float* __restrict__ W, const float* __restrict__ bias,
               float* __restrict__ U, float* __restrict__ posDst) {
  const int row = blockIdx.x;
  const int b = row / M;
  const int tid = threadIdx.x;
  const int j = fi[row];
  __shared__ float sx[CIN];
  if (tid < CIN) sx[tid] = X[((size_t)b * Nprev + j) * CIN + tid];
  if (tid < 3) posDst[(size_t)row * 3 + tid] = posPrev[((size_t)b * Nprev + j) * 3 + tid];
  __syncthreads();
  float a = bias[tid];
  for (int f = 0; f < CIN; f++) a = fmaf(sx[f], W[f * HH + tid], a);
  U[(size_t)row * HH + tid] = a;
}

// ---------------- global max pool + classifier/defense heads ----------------
__global__ __launch_bounds__(256) void head_kernel(
    const float* __restrict__ x3,
    const float* __restrict__ Wc1, const float* __restrict__ bc1,
    const float* __restrict__ Wc2, const float* __restrict__ bc2,
    const float* __restrict__ Wc3, const float* __restrict__ bc3,
    const float* __restrict__ Wd1, const float* __restrict__ bd1,
    const float* __restrict__ Wd2, const float* __restrict__ bd2,
    float* __restrict__ out) {
  const int b = blockIdx.x, tid = threadIdx.x;
  __shared__ float sf[256], sh[256], sh2[256], shd[256], sl[48];
  float mx = -1e9f;
  const float* __restrict__ xb = x3 + (size_t)b * 512 * 256;
  for (int p = 0; p < 512; p++) mx = fmaxf(mx, xb[p * 256 + tid]);
  sf[tid] = mx;
  __syncthreads();
  float a = bc1[tid], ad = bd1[tid];
  for (int f = 0; f < 256; f++) {
    const float fv = sf[f];
    a  = fmaf(fv, Wc1[f * 256 + tid], a);
    ad = fmaf(fv, Wd1[f * 256 + tid], ad);
  }
  sh[tid] = fmaxf(a, 0.f);
  shd[tid] = fmaxf(ad, 0.f);
  __syncthreads();
  float a2 = bc2[tid];
  for (int f = 0; f < 256; f++) a2 = fmaf(sh[f], Wc2[f * 256 + tid], a2);
  sh2[tid] = fmaxf(a2, 0.f);
  __syncthreads();
  if (tid < 40) {
    float l = bc3[tid];
    for (int f = 0; f < 256; f++) l = fmaf(sh2[f], Wc3[f * 40 + tid], l);
    sl[tid] = l;
  }
  if (tid >= 64 && tid < 66) {
    const int q = tid - 64;
    float l = bd2[q];
    for (int f = 0; f < 256; f++) l = fmaf(shd[f], Wd2[f * 2 + q], l);
    sl[40 + q] = l;
  }
  __syncthreads();
  if (tid == 0) {
    float m0 = sl[0];
    for (int q = 1; q < 40; q++) m0 = fmaxf(m0, sl[q]);
    float s = 0.f;
    for (int q = 0; q < 40; q++) s += expf(sl[q] - m0);
    const float ls = logf(s);
    for (int q = 0; q < 40; q++) out[b * 40 + q] = sl[q] - m0 - ls;
    const float m1 = fmaxf(sl[40], sl[41]);
    const float s1 = expf(sl[40] - m1) + expf(sl[41] - m1);
    const float ls1 = logf(s1);
    out[320 + b * 2 + 0] = sl[40] - m1 - ls1;
    out[320 + b * 2 + 1] = sl[41] - m1 - ls1;
  }
}

// ---------------------------------------------------------------------------
// LDS: FPS(N,NOUT) = N*16 + NOUT*4 + 32;  KC = max(N*8+13312, conv) + 528
static constexpr int SM1 = 82944;   // max(73784 fps, 46608 kc), pad >80KB -> 1 blk/CU
static constexpr int SM2 = 39440;   // max(34848 fps, 39440 kc)
static constexpr int SM3 = 57872;   // kc(512,256,256) @256thr -> 2 blk/CU

extern "C" void kernel_launch(void* const* d_in, const int* in_sizes, int n_in,
                              void* d_out, int out_size, void* d_ws, size_t ws_size,
                              hipStream_t stream) {
  (void)in_sizes; (void)n_in; (void)out_size; (void)ws_size;
  const float* pos = (const float*)d_in[0];
  const float* W1a = (const float*)d_in[1];  const float* b1a = (const float*)d_in[2];
  const float* W1b = (const float*)d_in[3];  const float* b1b = (const float*)d_in[4];
  const float* W2a = (const float*)d_in[5];  const float* b2a = (const float*)d_in[6];
  const float* W2b = (const float*)d_in[7];  const float* b2b = (const float*)d_in[8];
  const float* W3a = (const float*)d_in[9];  const float* b3a = (const float*)d_in[10];
  const float* W3b = (const float*)d_in[11]; const float* b3b = (const float*)d_in[12];
  const float* Wc1 = (const float*)d_in[13]; const float* bc1 = (const float*)d_in[14];
  const float* Wc2 = (const float*)d_in[15]; const float* bc2 = (const float*)d_in[16];
  const float* Wc3 = (const float*)d_in[17]; const float* bc3 = (const float*)d_in[18];
  const float* Wd1 = (const float*)d_in[19]; const float* bd1 = (const float*)d_in[20];
  const float* Wd2 = (const float*)d_in[21]; const float* bd2 = (const float*)d_in[22];
  float* out = (float*)d_out;

  char* w = (char*)d_ws;
  auto alloc = [&](size_t bytes) -> void* {
    void* p = (void*)w;
    w += (bytes + 255) & ~(size_t)255;
    return p;
  };
  int*   fi1  = (int*)  alloc((size_t)NB*2048*4);
  float* x1   = (float*)alloc((size_t)NB*4096*64*4);
  float* pos2 = (float*)alloc((size_t)NB*2048*3*4);
  float* U2   = (float*)alloc((size_t)NB*2048*128*4);
  float* x2   = (float*)alloc((size_t)NB*2048*128*4);
  int*   fi2  = (int*)  alloc((size_t)NB*512*4);
  float* pos3 = (float*)alloc((size_t)NB*512*3*4);
  float* U3   = (float*)alloc((size_t)NB*512*256*4);
  float* x3   = (float*)alloc((size_t)NB*512*256*4);

  // stage 1: {fps1 || knn1+conv1}  (both depend only on pos)
  stage_fused<4096, 2048, 64, 64, false, SM1>
      <<<NB + NB * 4096, 512, 0, stream>>>(
      pos, 0.2 * 0.2, fi1, nullptr, W1a, b1a, W1b, b1b, x1);

  // gather1 + preproj2 (U2 = x1[fi1] @ W2a[:64] + b2a)
  gp_kernel<64, 128><<<NB * 2048, 128, 0, stream>>>(
      x1, pos, fi1, 4096, 2048, W2a, b2a, U2, pos2);

  // stage 2: {fps2 || knn2+conv2}
  stage_fused<2048, 512, 128, 128, true, SM2>
      <<<NB + NB * 2048, 512, 0, stream>>>(
      pos2, 0.4 * 0.4, fi2, U2, W2a + (size_t)64 * 128, b2a, W2b, b2b, x2);

  // gather2 + preproj3
  gp_kernel<128, 256><<<NB * 512, 256, 0, stream>>>(
      x2, pos2, fi2, 2048, 512, W3a, b3a, U3, pos3);

  // stage 3: knn3+conv3
  stage_plain<512, 256, 256, true, SM3><<<NB * 512, 256, 0, stream>>>(
      pos3, 1.0, U3, W3a + (size_t)128 * 256, b3a, W3b, b3b, x3);

  // heads
  head_kernel<<<NB, 256, 0, stream>>>(x3, Wc1, bc1, Wc2, bc2, Wc3, bc3,
                                      Wd1, bd1, Wd2, bd2, out);
}

// Round 12
// 3026.979 us; speedup vs baseline: 1.0124x; 1.0124x over previous
//
#include <hip/hip_runtime.h>

// ---------------------------------------------------------------------------
// PointNet++ (defense variant) forward on MI355X.
// B=8, N=4096 -> 2048 -> 512, K=32 neighbors. Geometry is EXACT: positions are
// multiples of 2^-23 (f64 knn d2 / integer fps d2 are exact) — discrete
// choices match an np-f64 reference exactly.
// R12: revert R11 atomic ring (regressed: LDS u64 atomicMax is RMW-expensive).
// FPS update switched to exact f64 (3 sub + 3 FMA + min = 7 inst/elem vs ~19
// for i64; all quantities are integers < 2^48 so f64 is exact) — key packing
// ((u64)d2 << 12 | 4095-j) moves off the per-element path to once/thread/iter.
// stage3 at 512 threads (2 blk/CU, more waves for latency hiding).
// ---------------------------------------------------------------------------

#define NB 8

__device__ __forceinline__ unsigned obits(float f) {
  unsigned u = __float_as_uint(f);
  return (u & 0x80000000u) ? ~u : (u | 0x80000000u);
}

static constexpr int CAND = 1024;

// ---------------- DPP helpers (VALU cross-lane, no LDS pipe) ----------------
template<int CTRL>
__device__ __forceinline__ unsigned long long dpp_max_step(unsigned long long v) {
  const int lo = (int)(unsigned)(v & 0xffffffffull);
  const int hi = (int)(unsigned)(v >> 32);
  const unsigned nlo = (unsigned)__builtin_amdgcn_update_dpp(lo, lo, CTRL, 0xf, 0xf, false);
  const unsigned nhi = (unsigned)__builtin_amdgcn_update_dpp(hi, hi, CTRL, 0xf, 0xf, false);
  const unsigned long long nv = ((unsigned long long)nhi << 32) | nlo;
  return (nv > v) ? nv : v;
}

// wave64 inclusive prefix-sum (gfx9 DPP idiom; correctness-verified R9)
__device__ __forceinline__ unsigned wave_iscan_add(unsigned x) {
  x += (unsigned)__builtin_amdgcn_update_dpp(0, (int)x, 0x111, 0xf, 0xf, true); // shr1
  x += (unsigned)__builtin_amdgcn_update_dpp(0, (int)x, 0x112, 0xf, 0xf, true); // shr2
  x += (unsigned)__builtin_amdgcn_update_dpp(0, (int)x, 0x114, 0xf, 0xf, true); // shr4
  x += (unsigned)__builtin_amdgcn_update_dpp(0, (int)x, 0x118, 0xf, 0xf, true); // shr8
  x += (unsigned)__builtin_amdgcn_update_dpp(0, (int)x, 0x142, 0xa, 0xf, true); // bcast15
  x += (unsigned)__builtin_amdgcn_update_dpp(0, (int)x, 0x143, 0xc, 0xf, true); // bcast31
  return x;
}

__device__ __forceinline__ unsigned long long u64max(unsigned long long a,
                                                    unsigned long long b) {
  return (b > a) ? b : a;
}

// ---------------- FPS body (exact f64 update, integer key reduce) -----------
// d2 = dx^2+dy^2+dz^2 on the 2^23 integer grid: all values are integers
// < 2^48 — exact in f64 (< 2^53) under ANY op order. Per-thread best (v,e)
// is packed once/iter: key = ((u64)v << 12) | (4095 - j) => max key ==
// (max d2, tie -> min j). Cross-wave: partials array + redundant tree (R10).
template<int N, int NOUT, int T>
__device__ __forceinline__ void fps_body(char* sm, const float* __restrict__ pb,
                                         int* __restrict__ fi, int b) {
  constexpr int P = N / T;
  constexpr int NW = T / 64;
  int4* sPosI = (int4*)sm;                                   // [N]
  int*  sfi   = (int*)(sm + (size_t)N * 16);                 // [NOUT]
  unsigned long long* sKey =
      (unsigned long long*)(sm + (size_t)N * 16 + NOUT * 4); // [2][NW]
  const int tid = threadIdx.x, wid = tid >> 6, lane = tid & 63;
  double px[P], py[P], pz[P], mind[P];
  for (int t = tid; t < N; t += T) {
    sPosI[t] = make_int4((int)(pb[3*t]   * 8388608.f),   // exact: 2^-23 multiples
                         (int)(pb[3*t+1] * 8388608.f),
                         (int)(pb[3*t+2] * 8388608.f), 0);
  }
  __syncthreads();
  const double x0 = (double)sPosI[0].x, y0 = (double)sPosI[0].y,
               z0 = (double)sPosI[0].z;
  double bv; int bi;
  {
    double tv[P]; int te[P];
#pragma unroll
    for (int e = 0; e < P; e++) {
      const int j = tid * P + e;
      const int4 p4 = sPosI[j];
      const double x = (double)p4.x, y = (double)p4.y, z = (double)p4.z;
      px[e] = x; py[e] = y; pz[e] = z;
      const double dx = x - x0, dy = y - y0, dz = z - z0;
      const double d = fma(dx, dx, fma(dy, dy, dz * dz));    // exact integer
      mind[e] = d; tv[e] = d; te[e] = e;
    }
#pragma unroll
    for (int s = 1; s < P; s <<= 1)
#pragma unroll
      for (int e = 0; e + s < P; e += 2 * s)
        if (tv[e + s] > tv[e]) { tv[e] = tv[e + s]; te[e] = te[e + s]; } // tie->low e
    bv = tv[0]; bi = tid * P + te[0];
  }
  if (tid == 0) sfi[0] = 0;
  for (int t = 1; t < NOUT; t++) {
    // pack once per thread per iteration (off the per-element path)
    const unsigned long long u = (unsigned long long)bv;     // exact, < 2^48
    unsigned long long v = (u << 12) | (unsigned)(4095 - bi);
    v = dpp_max_step<0x111>(v);   // row_shr:1
    v = dpp_max_step<0x112>(v);   // row_shr:2
    v = dpp_max_step<0x114>(v);   // row_shr:4
    v = dpp_max_step<0x118>(v);   // row_shr:8
    v = dpp_max_step<0x142>(v);   // row_bcast:15
    v = dpp_max_step<0x143>(v);   // row_bcast:31
    const int pp = t & 1;
    if (lane == 63) sKey[pp * NW + wid] = v;
    __syncthreads();   // only barrier per iter; LDS-only (no vmcnt drain)
    unsigned long long best;
    if (NW == 8) {
      unsigned long long k0 = sKey[pp*8+0], k1 = sKey[pp*8+1],
                         k2 = sKey[pp*8+2], k3 = sKey[pp*8+3],
                         k4 = sKey[pp*8+4], k5 = sKey[pp*8+5],
                         k6 = sKey[pp*8+6], k7 = sKey[pp*8+7];
      k0 = u64max(k0, k1); k2 = u64max(k2, k3);
      k4 = u64max(k4, k5); k6 = u64max(k6, k7);
      k0 = u64max(k0, k2); k4 = u64max(k4, k6);
      best = u64max(k0, k4);
    } else {
      unsigned long long k0 = sKey[pp*NW+0];
#pragma unroll
      for (int w2 = 1; w2 < NW; w2++) k0 = u64max(k0, sKey[pp*NW+w2]);
      best = k0;
    }
    const int ii = 4095 - (int)(best & 0xFFFull);
    if (tid == 0) sfi[t] = ii;
    const int4 wc4 = sPosI[ii];   // single b128 same-address broadcast
    const double wx = (double)wc4.x, wy = (double)wc4.y, wz = (double)wc4.z;
    double tv[P]; int te[P];
#pragma unroll
    for (int e = 0; e < P; e++) {
      const double dx = px[e] - wx, dy = py[e] - wy, dz = pz[e] - wz;
      const double nd = fma(dx, dx, fma(dy, dy, dz * dz));   // exact integer
      double mn = mind[e];
      mn = (nd < mn) ? nd : mn;
      mind[e] = mn;
      tv[e] = mn; te[e] = e;
    }
#pragma unroll
    for (int s = 1; s < P; s <<= 1)
#pragma unroll
      for (int e = 0; e + s < P; e += 2 * s)
        if (tv[e + s] > tv[e]) { tv[e] = tv[e + s]; te[e] = te[e + s]; } // tie->low e
    bv = tv[0]; bi = tid * P + te[0];
  }
  __syncthreads();
  for (int t = tid; t < NOUT; t += T) fi[(size_t)b * NOUT + t] = sfi[t];
}

// ---------------- knn (exact f64 top-32, LDS d2s) + conv fused per row ------
template<int N, int H, int C, bool HASX, int T>
__device__ __forceinline__ void knnconv_body(
    char* sm, const float* __restrict__ pb, int b, int i,
    const float* __restrict__ U, const float* __restrict__ Wrel,
    const float* __restrict__ b1, const float* __restrict__ W2,
    const float* __restrict__ b2, float* __restrict__ out, double rr) {
  constexpr int HCHUNK = (C == 64) ? 64 : (C == 128 ? 32 : 16);
  constexpr int STR = HCHUNK + 4;
  constexpr int NW = T / 64;        // k-groups
  constexpr int EPK = 32 / NW;      // k's per thread
  constexpr int BPT = 2048 / T;     // histogram bins per thread
  constexpr int KNNFRONT = N * 8 + 13312;
  constexpr int CONVFRONT = 32 * H * 4 + C * STR * 4 + NW * C * 4;
  constexpr int FRONT = (KNNFRONT > CONVFRONT) ? KNNFRONT : CONVFRONT;
  // knn views
  double*   d2s     = (double*)sm;                        // [N]
  unsigned* hist    = (unsigned*)(sm + N * 8);            // [2048]
  int*      candIdx = (int*)(sm + N * 8 + 8192);          // [CAND]
  unsigned* sWT     = (unsigned*)(sm + N * 8 + 12288);    // [NW]
  // conv views (alias the knn front; born after ranking completes)
  float* h1s  = (float*)sm;                               // [32*H]
  float* sW2T = (float*)(sm + 32 * H * 4);                // [C*STR]
  float* sRed = (float*)(sm + 32 * H * 4 + C * STR * 4);  // [NW][C]
  // tail (never aliased)
  int*   snbr = (int*)(sm + FRONT);                       // [32]
  float* rel  = (float*)(sm + FRONT + 128);               // [32][3]
  int*   pcnt = (int*)(sm + FRONT + 128 + 384);
  int*   pbin = pcnt + 1;
  const int tid = threadIdx.x;

  // --- distance pass: exact f64 d2 into LDS ---
  const double xi = pb[3*i], yi = pb[3*i+1], zi = pb[3*i+2];
  const double si = (xi*xi + yi*yi) + zi*zi;
  for (int t = tid; t < 2048; t += T) hist[t] = 0u;
  if (tid == 0) *pcnt = 0;
  __syncthreads();
  for (int j = tid; j < N; j += T) {
    double xj = pb[3*j], yj = pb[3*j+1], zj = pb[3*j+2];
    double sj = (xj*xj + yj*yj) + zj*zj;
    double dt = (xi*xj + yi*yj) + zi*zj;
    double d2 = (si + sj) - 2.0*dt;       // exact in f64
    if (j == i) d2 += 1e9;                // self-exclusion
    d2s[j] = d2;
    atomicAdd(&hist[obits((float)d2) >> 21], 1u);
  }
  __syncthreads();
  // --- bin threshold via DPP scan ---
  unsigned lsum = 0;
  const int base = tid * BPT;
#pragma unroll
  for (int q = 0; q < BPT; q++) lsum += hist[base + q];
  const unsigned isc = wave_iscan_add(lsum);
  if ((tid & 63) == 63) sWT[tid >> 6] = isc;
  __syncthreads();
  {
    const int wid = tid >> 6;
    unsigned offs = 0;
#pragma unroll
    for (int w2 = 0; w2 < NW; w2++) offs += (w2 < wid) ? sWT[w2] : 0u;
    const unsigned incl = isc + offs, excl = incl - lsum;
    if (excl < 32u && incl >= 32u) {
      unsigned c = excl;
      for (int q = 0; q < BPT; q++) {
        c += hist[base + q];
        if (c >= 32u) { *pbin = base + q; break; }
      }
    }
  }
  __syncthreads();
  const int binT = *pbin;
  for (int j = tid; j < N; j += T) {
    if ((int)(obits((float)d2s[j]) >> 21) <= binT) {
      int p = atomicAdd(pcnt, 1);
      if (p < CAND) candIdx[p] = j;
    }
  }
  __syncthreads();
  const int M = min(*pcnt, CAND);   // true top-32 superset (proxy monotone)
  for (int c = tid; c < M; c += T) {
    const int j = candIdx[c];
    const double d = d2s[j];
    int rank = 0;
    for (int e = 0; e < M; e++) {
      const int j2 = candIdx[e];
      const double de = d2s[j2];
      rank += (de < d || (de == d && j2 < j)) ? 1 : 0;
    }
    if (rank < 32) snbr[rank] = (d <= rr) ? j : -1;
  }
  __syncthreads();                 // knn LDS dead from here; snbr valid

  // --- rel ---
  if (tid < 32) {
    const int j = snbr[tid];
    float rx = 0.f, ry = 0.f, rz = 0.f;
    if (j >= 0) {
      rx = pb[3*j]   - pb[3*i];
      ry = pb[3*j+1] - pb[3*i+1];
      rz = pb[3*j+2] - pb[3*i+2];
    }
    rel[tid*3+0] = rx; rel[tid*3+1] = ry; rel[tid*3+2] = rz;
  }
  __syncthreads();

  // --- conv phase B: h1[k][h0..h0+3] = relu(U[j] (+b1) + rel . Wrel) ---
  constexpr int QPK = H / 4;
  for (int qi = tid; qi < 32 * QPK; qi += T) {
    const int k = qi / QPK, h0 = (qi - k * QPK) * 4;
    const int j = snbr[k];
    float4 v = make_float4(0.f, 0.f, 0.f, 0.f);
    if (j >= 0) {
      float4 a = HASX ? *(const float4*)&U[((size_t)b * N + j) * H + h0]
                      : *(const float4*)&b1[h0];
      const float rx = rel[k*3], ry = rel[k*3+1], rz = rel[k*3+2];
      const float4 w0 = *(const float4*)&Wrel[h0];
      const float4 w1 = *(const float4*)&Wrel[H + h0];
      const float4 w2 = *(const float4*)&Wrel[2 * H + h0];
      a.x += rx * w0.x + ry * w1.x + rz * w2.x;
      a.y += rx * w0.y + ry * w1.y + rz * w2.y;
      a.z += rx * w0.z + ry * w1.z + rz * w2.z;
      a.w += rx * w0.w + ry * w1.w + rz * w2.w;
      v = make_float4(fmaxf(a.x, 0.f), fmaxf(a.y, 0.f),
                      fmaxf(a.z, 0.f), fmaxf(a.w, 0.f));
    }
    *(float4*)&h1s[k * H + h0] = v;
  }
  const int cc = tid & 63;
  const int kk = tid >> 6;          // 0..NW-1
  constexpr int CC = C / 64;
  float acc[EPK][CC];
#pragma unroll
  for (int e = 0; e < EPK; e++)
#pragma unroll
    for (int q = 0; q < CC; q++) acc[e][q] = 0.f;
  // --- conv phase C: h2 = h1 @ W2 (W2 staged transposed+padded) ---
  for (int hc = 0; hc < H; hc += HCHUNK) {
    __syncthreads();
    for (int idx = tid; idx < HCHUNK * C; idx += T) {
      const int hh = idx / C, c = idx - hh * C;
      sW2T[c * STR + hh] = W2[(size_t)(hc + hh) * C + c];
    }
    __syncthreads();
    for (int hh0 = 0; hh0 < HCHUNK; hh0 += 4) {
      float4 wv[CC];
#pragma unroll
      for (int q = 0; q < CC; q++)
        wv[q] = *(const float4*)&sW2T[(cc + q * 64) * STR + hh0];
#pragma unroll
      for (int e = 0; e < EPK; e++) {
        const float4 hv = *(const float4*)&h1s[(kk + e * NW) * H + hc + hh0];
#pragma unroll
        for (int q = 0; q < CC; q++) {
          acc[e][q] += hv.x * wv[q].x;
          acc[e][q] += hv.y * wv[q].y;
          acc[e][q] += hv.z * wv[q].z;
          acc[e][q] += hv.w * wv[q].w;
        }
      }
    }
  }
  // --- masked max over k, +b2, relu ---
  float m[CC];
#pragma unroll
  for (int q = 0; q < CC; q++) m[q] = -1e9f;
#pragma unroll
  for (int e = 0; e < EPK; e++) {
    if (snbr[kk + e * NW] >= 0) {
#pragma unroll
      for (int q = 0; q < CC; q++) m[q] = fmaxf(m[q], acc[e][q]);
    }
  }
#pragma unroll
  for (int q = 0; q < CC; q++) sRed[kk * C + cc + q * 64] = m[q];
  __syncthreads();
  if (kk == 0) {
#pragma unroll
    for (int q = 0; q < CC; q++) {
      const int c = cc + q * 64;
      float mm = sRed[c];
#pragma unroll
      for (int w2 = 1; w2 < NW; w2++) mm = fmaxf(mm, sRed[w2 * C + c]);
      const float o = (mm > -5e8f) ? (mm + b2[c]) : -1e9f;
      out[((size_t)b * N + i) * C + c] = fmaxf(o, 0.f);
    }
  }
}

// ---------------- fused stage: blocks 0..NB-1 = FPS, rest = knn+conv --------
template<int N, int NOUT, int H, int C, bool HASX, int SMSIZE>
__global__ __attribute__((amdgpu_waves_per_eu(2, 2))) __launch_bounds__(512, 2)
void stage_fused(const float* __restrict__ pos, double rr, int* __restrict__ fi,
                 const float* __restrict__ U, const float* __restrict__ Wrel,
                 const float* __restrict__ b1, const float* __restrict__ W2,
                 const float* __restrict__ b2, float* __restrict__ out) {
  __shared__ __align__(16) char sm[SMSIZE];
  if (blockIdx.x < NB) {
    fps_body<N, NOUT, 512>(sm, pos + (size_t)blockIdx.x * N * 3, fi, blockIdx.x);
  } else {
    const int row = blockIdx.x - NB;
    const int b = row / N;
    const int i = row - b * N;
    knnconv_body<N, H, C, HASX, 512>(sm, pos + (size_t)b * N * 3, b, i,
                                     U, Wrel, b1, W2, b2, out, rr);
  }
}

// ---------------- stage 3: knn+conv only (512 threads, 2 blk/CU) ------------
template<int N, int H, int C, bool HASX, int SMSIZE>
__global__ __launch_bounds__(512)
void stage_plain(const float* __restrict__ pos, double rr,
                 const float* __restrict__ U, const float* __restrict__ Wrel,
                 const float* __restrict__ b1, const float* __restrict__ W2,
                 const float* __restrict__ b2, float* __restrict__ out) {
  __shared__ __align__(16) char sm[SMSIZE];
  const int b = blockIdx.x / N;
  const int i = blockIdx.x - b * N;
  knnconv_body<N, H, C, HASX, 512>(sm, pos + (size_t)b * N * 3, b, i,
                                   U, Wrel, b1, W2, b2, out, rr);
}

// ---------------- fused gather + preproj (U = x[fi] @ W[:CIN] + b) ----------
template<int CIN, int HH>
__global__ __launch_bounds__(HH)
void gp_kernel(const float* __restrict__ X, const float* __restrict__ posPrev,
               const int* __restrict__ fi, int Nprev, int M,
               const float* __restrict__ W, const float* __restrict__ bias,
               float* __restrict__ U, float* __restrict__ posDst) {
  const int row = blockIdx.x;
  const int b = row / M;
  const int tid = threadIdx.x;
  const int j = fi[row];
  __shared__ float sx[CIN];
  if (tid < CIN) sx[tid] = X[((size_t)b * Nprev + j) * CIN + tid];
  if (tid < 3) posDst[(size_t)row * 3 + tid] = posPrev[((size_t)b * Nprev + j) * 3 + tid];
  __syncthreads();
  float a = bias[tid];
  for (int f = 0; f < CIN; f++) a = fmaf(sx[f], W[f * HH + tid], a);
  U[(size_t)row * HH + tid] = a;
}

// ---------------- global max pool + classifier/defense heads ----------------
__global__ __launch_bounds__(256) void head_kernel(
    const float* __restrict__ x3,
    const float* __restrict__ Wc1, const float* __restrict__ bc1,
    const float* __restrict__ Wc2, const float* __restrict__ bc2,
    const float* __restrict__ Wc3, const float* __restrict__ bc3,
    const float* __restrict__ Wd1, const float* __restrict__ bd1,
    const float* __restrict__ Wd2, const float* __restrict__ bd2,
    float* __restrict__ out) {
  const int b = blockIdx.x, tid = threadIdx.x;
  __shared__ float sf[256], sh[256], sh2[256], shd[256], sl[48];
  float mx = -1e9f;
  const float* __restrict__ xb = x3 + (size_t)b * 512 * 256;
  for (int p = 0; p < 512; p++) mx = fmaxf(mx, xb[p * 256 + tid]);
  sf[tid] = mx;
  __syncthreads();
  float a = bc1[tid], ad = bd1[tid];
  for (int f = 0; f < 256; f++) {
    const float fv = sf[f];
    a  = fmaf(fv, Wc1[f * 256 + tid], a);
    ad = fmaf(fv, Wd1[f * 256 + tid], ad);
  }
  sh[tid] = fmaxf(a, 0.f);
  shd[tid] = fmaxf(ad, 0.f);
  __syncthreads();
  float a2 = bc2[tid];
  for (int f = 0; f < 256; f++) a2 = fmaf(sh[f], Wc2[f * 256 + tid], a2);
  sh2[tid] = fmaxf(a2, 0.f);
  __syncthreads();
  if (tid < 40) {
    float l = bc3[tid];
    for (int f = 0; f < 256; f++) l = fmaf(sh2[f], Wc3[f * 40 + tid], l);
    sl[tid] = l;
  }
  if (tid >= 64 && tid < 66) {
    const int q = tid - 64;
    float l = bd2[q];
    for (int f = 0; f < 256; f++) l = fmaf(shd[f], Wd2[f * 2 + q], l);
    sl[40 + q] = l;
  }
  __syncthreads();
  if (tid == 0) {
    float m0 = sl[0];
    for (int q = 1; q < 40; q++) m0 = fmaxf(m0, sl[q]);
    float s = 0.f;
    for (int q = 0; q < 40; q++) s += expf(sl[q] - m0);
    const float ls = logf(s);
    for (int q = 0; q < 40; q++) out[b * 40 + q] = sl[q] - m0 - ls;
    const float m1 = fmaxf(sl[40], sl[41]);
    const float s1 = expf(sl[40] - m1) + expf(sl[41] - m1);
    const float ls1 = logf(s1);
    out[320 + b * 2 + 0] = sl[40] - m1 - ls1;
    out[320 + b * 2 + 1] = sl[41] - m1 - ls1;
  }
}

// ---------------------------------------------------------------------------
// LDS: FPS(N,NOUT) = N*16 + NOUT*4 + 128;  KC = max(N*8+13312, conv) + 528
static constexpr int SM1 = 82944;   // max(73984 fps, 46608 kc), pad >80KB -> 1 blk/CU
static constexpr int SM2 = 39440;   // max(34944 fps, 39440 kc)
static constexpr int SM3 = 61968;   // kc(512,256,256) @512thr -> 2 blk/CU

extern "C" void kernel_launch(void* const* d_in, const int* in_sizes, int n_in,
                              void* d_out, int out_size, void* d_ws, size_t ws_size,
                              hipStream_t stream) {
  (void)in_sizes; (void)n_in; (void)out_size; (void)ws_size;
  const float* pos = (const float*)d_in[0];
  const float* W1a = (const float*)d_in[1];  const float* b1a = (const float*)d_in[2];
  const float* W1b = (const float*)d_in[3];  const float* b1b = (const float*)d_in[4];
  const float* W2a = (const float*)d_in[5];  const float* b2a = (const float*)d_in[6];
  const float* W2b = (const float*)d_in[7];  const float* b2b = (const float*)d_in[8];
  const float* W3a = (const float*)d_in[9];  const float* b3a = (const float*)d_in[10];
  const float* W3b = (const float*)d_in[11]; const float* b3b = (const float*)d_in[12];
  const float* Wc1 = (const float*)d_in[13]; const float* bc1 = (const float*)d_in[14];
  const float* Wc2 = (const float*)d_in[15]; const float* bc2 = (const float*)d_in[16];
  const float* Wc3 = (const float*)d_in[17]; const float* bc3 = (const float*)d_in[18];
  const float* Wd1 = (const float*)d_in[19]; const float* bd1 = (const float*)d_in[20];
  const float* Wd2 = (const float*)d_in[21]; const float* bd2 = (const float*)d_in[22];
  float* out = (float*)d_out;

  char* w = (char*)d_ws;
  auto alloc = [&](size_t bytes) -> void* {
    void* p = (void*)w;
    w += (bytes + 255) & ~(size_t)255;
    return p;
  };
  int*   fi1  = (int*)  alloc((size_t)NB*2048*4);
  float* x1   = (float*)alloc((size_t)NB*4096*64*4);
  float* pos2 = (float*)alloc((size_t)NB*2048*3*4);
  float* U2   = (float*)alloc((size_t)NB*2048*128*4);
  float* x2   = (float*)alloc((size_t)NB*2048*128*4);
  int*   fi2  = (int*)  alloc((size_t)NB*512*4);
  float* pos3 = (float*)alloc((size_t)NB*512*3*4);
  float* U3   = (float*)alloc((size_t)NB*512*256*4);
  float* x3   = (float*)alloc((size_t)NB*512*256*4);

  // stage 1: {fps1 || knn1+conv1}  (both depend only on pos)
  stage_fused<4096, 2048, 64, 64, false, SM1>
      <<<NB + NB * 4096, 512, 0, stream>>>(
      pos, 0.2 * 0.2, fi1, nullptr, W1a, b1a, W1b, b1b, x1);

  // gather1 + preproj2 (U2 = x1[fi1] @ W2a[:64] + b2a)
  gp_kernel<64, 128><<<NB * 2048, 128, 0, stream>>>(
      x1, pos, fi1, 4096, 2048, W2a, b2a, U2, pos2);

  // stage 2: {fps2 || knn2+conv2}
  stage_fused<2048, 512, 128, 128, true, SM2>
      <<<NB + NB * 2048, 512, 0, stream>>>(
      pos2, 0.4 * 0.4, fi2, U2, W2a + (size_t)64 * 128, b2a, W2b, b2b, x2);

  // gather2 + preproj3
  gp_kernel<128, 256><<<NB * 512, 256, 0, stream>>>(
      x2, pos2, fi2, 2048, 512, W3a, b3a, U3, pos3);

  // stage 3: knn3+conv3
  stage_plain<512, 256, 256, true, SM3><<<NB * 512, 512, 0, stream>>>(
      pos3, 1.0, U3, W3a + (size_t)128 * 256, b3a, W3b, b3b, x3);

  // heads
  head_kernel<<<NB, 256, 0, stream>>>(x3, Wc1, bc1, Wc2, bc2, Wc3, bc3,
                                      Wd1, bd1, Wd2, bd2, out);
}

// Round 13
// 2899.539 us; speedup vs baseline: 1.0569x; 1.0440x over previous
//
#include <hip/hip_runtime.h>

// ---------------------------------------------------------------------------
// PointNet++ (defense variant) forward on MI355X.
// B=8, N=4096 -> 2048 -> 512, K=32 neighbors. Geometry is EXACT: positions are
// multiples of 2^-23 (f64 knn d2 / i64 fps d2 are exact) — discrete choices
// match an np-f64 reference exactly.
// R13: revert R12 f64 update (f64 = 4cyc/inst vs i64 mad 2cyc — measured
// regression). s_setprio(3) on fps waves (stage2 fps shares CUs with 3
// knnconv blocks; priority protects the serial chain). Global max-pool folded
// into stage3 via int-atomicMax on non-negative floats (x3 eliminated; head
// reads feat directly). Distinct kernel names for per-stage profiling.
// ---------------------------------------------------------------------------

#define NB 8

__device__ __forceinline__ unsigned obits(float f) {
  unsigned u = __float_as_uint(f);
  return (u & 0x80000000u) ? ~u : (u | 0x80000000u);
}

static constexpr int CAND = 1024;

// ---------------- DPP helpers (VALU cross-lane, no LDS pipe) ----------------
template<int CTRL>
__device__ __forceinline__ unsigned long long dpp_max_step(unsigned long long v) {
  const int lo = (int)(unsigned)(v & 0xffffffffull);
  const int hi = (int)(unsigned)(v >> 32);
  const unsigned nlo = (unsigned)__builtin_amdgcn_update_dpp(lo, lo, CTRL, 0xf, 0xf, false);
  const unsigned nhi = (unsigned)__builtin_amdgcn_update_dpp(hi, hi, CTRL, 0xf, 0xf, false);
  const unsigned long long nv = ((unsigned long long)nhi << 32) | nlo;
  return (nv > v) ? nv : v;
}

// wave64 inclusive prefix-sum (gfx9 DPP idiom; correctness-verified R9)
__device__ __forceinline__ unsigned wave_iscan_add(unsigned x) {
  x += (unsigned)__builtin_amdgcn_update_dpp(0, (int)x, 0x111, 0xf, 0xf, true); // shr1
  x += (unsigned)__builtin_amdgcn_update_dpp(0, (int)x, 0x112, 0xf, 0xf, true); // shr2
  x += (unsigned)__builtin_amdgcn_update_dpp(0, (int)x, 0x114, 0xf, 0xf, true); // shr4
  x += (unsigned)__builtin_amdgcn_update_dpp(0, (int)x, 0x118, 0xf, 0xf, true); // shr8
  x += (unsigned)__builtin_amdgcn_update_dpp(0, (int)x, 0x142, 0xa, 0xf, true); // bcast15
  x += (unsigned)__builtin_amdgcn_update_dpp(0, (int)x, 0x143, 0xc, 0xf, true); // bcast31
  return x;
}

__device__ __forceinline__ unsigned long long u64max(unsigned long long a,
                                                    unsigned long long b) {
  return (b > a) ? b : a;
}

__device__ __forceinline__ void set_wave_prio_hi() {
#if __has_builtin(__builtin_amdgcn_s_setprio)
  __builtin_amdgcn_s_setprio(3);
#endif
}

// ---------------- FPS body (R10-exact integer keys, deterministic) ----------
// key = (d2 << 12) | (4095 - j)  =>  max key == (max d2, tie -> min j).
// i64 update via v_mad_u64_u32 (full-rate); per-wave DPP u64-max; partials
// array + redundant tree (R10 config — the verified fastest variant).
template<int N, int NOUT, int T>
__device__ __forceinline__ void fps_body(char* sm, const float* __restrict__ pb,
                                         int* __restrict__ fi, int b) {
  constexpr int P = N / T;
  constexpr int NW = T / 64;
  int4* sPosI = (int4*)sm;                                   // [N]
  int*  sfi   = (int*)(sm + (size_t)N * 16);                 // [NOUT]
  unsigned long long* sKey =
      (unsigned long long*)(sm + (size_t)N * 16 + NOUT * 4); // [2][NW]
  const int tid = threadIdx.x, wid = tid >> 6, lane = tid & 63;
  set_wave_prio_hi();    // protect the serial chain from co-resident waves
  int ix[P], iy[P], iz[P];
  unsigned long long mind[P];
  for (int t = tid; t < N; t += T) {
    sPosI[t] = make_int4((int)(pb[3*t]   * 8388608.f),   // exact: 2^-23 multiples
                         (int)(pb[3*t+1] * 8388608.f),
                         (int)(pb[3*t+2] * 8388608.f), 0);
  }
  __syncthreads();
  const int x0 = sPosI[0].x, y0 = sPosI[0].y, z0 = sPosI[0].z;
  const int invBase = 4095 - tid * P;
  unsigned long long bv;
  {
    unsigned long long tv[P];
#pragma unroll
    for (int e = 0; e < P; e++) {
      const int j = tid * P + e;
      const int4 p4 = sPosI[j];
      ix[e] = p4.x; iy[e] = p4.y; iz[e] = p4.z;
      const long long dx = p4.x - x0, dy = p4.y - y0, dz = p4.z - z0;
      const unsigned long long d2 =
          (unsigned long long)(dx * dx + dy * dy + dz * dz);   // exact, < 2^48
      const unsigned long long k = (d2 << 12) | (unsigned)(invBase - e);
      mind[e] = k; tv[e] = k;
    }
#pragma unroll
    for (int s = 1; s < P; s <<= 1)
#pragma unroll
      for (int e = 0; e + s < P; e += 2 * s)
        if (tv[e + s] > tv[e]) tv[e] = tv[e + s];
    bv = tv[0];
  }
  if (tid == 0) sfi[0] = 0;
  for (int t = 1; t < NOUT; t++) {
    unsigned long long v = bv;
    v = dpp_max_step<0x111>(v);   // row_shr:1
    v = dpp_max_step<0x112>(v);   // row_shr:2
    v = dpp_max_step<0x114>(v);   // row_shr:4
    v = dpp_max_step<0x118>(v);   // row_shr:8
    v = dpp_max_step<0x142>(v);   // row_bcast:15
    v = dpp_max_step<0x143>(v);   // row_bcast:31
    const int pp = t & 1;
    if (lane == 63) sKey[pp * NW + wid] = v;
    __syncthreads();   // only barrier per iter; LDS-only (no vmcnt drain)
    unsigned long long best;
    if (NW == 8) {
      unsigned long long k0 = sKey[pp*8+0], k1 = sKey[pp*8+1],
                         k2 = sKey[pp*8+2], k3 = sKey[pp*8+3],
                         k4 = sKey[pp*8+4], k5 = sKey[pp*8+5],
                         k6 = sKey[pp*8+6], k7 = sKey[pp*8+7];
      k0 = u64max(k0, k1); k2 = u64max(k2, k3);
      k4 = u64max(k4, k5); k6 = u64max(k6, k7);
      k0 = u64max(k0, k2); k4 = u64max(k4, k6);
      best = u64max(k0, k4);
    } else {
      unsigned long long k0 = sKey[pp*NW+0];
#pragma unroll
      for (int w2 = 1; w2 < NW; w2++) k0 = u64max(k0, sKey[pp*NW+w2]);
      best = k0;
    }
    const int ii = 4095 - (int)(best & 0xFFFull);
    if (tid == 0) sfi[t] = ii;
    const int4 wc = sPosI[ii];    // single b128 same-address broadcast
    unsigned long long tv[P];
#pragma unroll
    for (int e = 0; e < P; e++) {
      const long long dx = ix[e] - wc.x, dy = iy[e] - wc.y, dz = iz[e] - wc.z;
      const unsigned long long nd =
          (unsigned long long)(dx * dx + dy * dy + dz * dz);
      const unsigned long long nk = (nd << 12) | (unsigned)(invBase - e);
      unsigned long long mk = mind[e];
      mk = (nk < mk) ? nk : mk;
      mind[e] = mk;
      tv[e] = mk;
    }
#pragma unroll
    for (int s = 1; s < P; s <<= 1)
#pragma unroll
      for (int e = 0; e + s < P; e += 2 * s)
        if (tv[e + s] > tv[e]) tv[e] = tv[e + s];
    bv = tv[0];
  }
  __syncthreads();
  for (int t = tid; t < NOUT; t += T) fi[(size_t)b * NOUT + t] = sfi[t];
}

// ---------------- knn (exact f64 top-32, LDS d2s) + conv fused per row ------
// FOLDMAX: instead of storing out[row][c], atomicMax the post-relu value
// (>= 0, IEEE bits int-order-isomorphic) into feat[b][c] (global max pool).
template<int N, int H, int C, bool HASX, bool FOLDMAX, int T>
__device__ __forceinline__ void knnconv_body(
    char* sm, const float* __restrict__ pb, int b, int i,
    const float* __restrict__ U, const float* __restrict__ Wrel,
    const float* __restrict__ b1, const float* __restrict__ W2,
    const float* __restrict__ b2, float* __restrict__ out, double rr) {
  constexpr int HCHUNK = (C == 64) ? 64 : (C == 128 ? 32 : 16);
  constexpr int STR = HCHUNK + 4;
  constexpr int NW = T / 64;        // k-groups
  constexpr int EPK = 32 / NW;      // k's per thread
  constexpr int BPT = 2048 / T;     // histogram bins per thread
  constexpr int KNNFRONT = N * 8 + 13312;
  constexpr int CONVFRONT = 32 * H * 4 + C * STR * 4 + NW * C * 4;
  constexpr int FRONT = (KNNFRONT > CONVFRONT) ? KNNFRONT : CONVFRONT;
  // knn views
  double*   d2s     = (double*)sm;                        // [N]
  unsigned* hist    = (unsigned*)(sm + N * 8);            // [2048]
  int*      candIdx = (int*)(sm + N * 8 + 8192);          // [CAND]
  unsigned* sWT     = (unsigned*)(sm + N * 8 + 12288);    // [NW]
  // conv views (alias the knn front; born after ranking completes)
  float* h1s  = (float*)sm;                               // [32*H]
  float* sW2T = (float*)(sm + 32 * H * 4);                // [C*STR]
  float* sRed = (float*)(sm + 32 * H * 4 + C * STR * 4);  // [NW][C]
  // tail (never aliased)
  int*   snbr = (int*)(sm + FRONT);                       // [32]
  float* rel  = (float*)(sm + FRONT + 128);               // [32][3]
  int*   pcnt = (int*)(sm + FRONT + 128 + 384);
  int*   pbin = pcnt + 1;
  const int tid = threadIdx.x;

  // --- distance pass: exact f64 d2 into LDS ---
  const double xi = pb[3*i], yi = pb[3*i+1], zi = pb[3*i+2];
  const double si = (xi*xi + yi*yi) + zi*zi;
  for (int t = tid; t < 2048; t += T) hist[t] = 0u;
  if (tid == 0) *pcnt = 0;
  __syncthreads();
  for (int j = tid; j < N; j += T) {
    double xj = pb[3*j], yj = pb[3*j+1], zj = pb[3*j+2];
    double sj = (xj*xj + yj*yj) + zj*zj;
    double dt = (xi*xj + yi*yj) + zi*zj;
    double d2 = (si + sj) - 2.0*dt;       // exact in f64
    if (j == i) d2 += 1e9;                // self-exclusion
    d2s[j] = d2;
    atomicAdd(&hist[obits((float)d2) >> 21], 1u);
  }
  __syncthreads();
  // --- bin threshold via DPP scan ---
  unsigned lsum = 0;
  const int base = tid * BPT;
#pragma unroll
  for (int q = 0; q < BPT; q++) lsum += hist[base + q];
  const unsigned isc = wave_iscan_add(lsum);
  if ((tid & 63) == 63) sWT[tid >> 6] = isc;
  __syncthreads();
  {
    const int wid = tid >> 6;
    unsigned offs = 0;
#pragma unroll
    for (int w2 = 0; w2 < NW; w2++) offs += (w2 < wid) ? sWT[w2] : 0u;
    const unsigned incl = isc + offs, excl = incl - lsum;
    if (excl < 32u && incl >= 32u) {
      unsigned c = excl;
      for (int q = 0; q < BPT; q++) {
        c += hist[base + q];
        if (c >= 32u) { *pbin = base + q; break; }
      }
    }
  }
  __syncthreads();
  const int binT = *pbin;
  for (int j = tid; j < N; j += T) {
    if ((int)(obits((float)d2s[j]) >> 21) <= binT) {
      int p = atomicAdd(pcnt, 1);
      if (p < CAND) candIdx[p] = j;
    }
  }
  __syncthreads();
  const int M = min(*pcnt, CAND);   // true top-32 superset (proxy monotone)
  for (int c = tid; c < M; c += T) {
    const int j = candIdx[c];
    const double d = d2s[j];
    int rank = 0;
    for (int e = 0; e < M; e++) {
      const int j2 = candIdx[e];
      const double de = d2s[j2];
      rank += (de < d || (de == d && j2 < j)) ? 1 : 0;
    }
    if (rank < 32) snbr[rank] = (d <= rr) ? j : -1;
  }
  __syncthreads();                 // knn LDS dead from here; snbr valid

  // --- rel ---
  if (tid < 32) {
    const int j = snbr[tid];
    float rx = 0.f, ry = 0.f, rz = 0.f;
    if (j >= 0) {
      rx = pb[3*j]   - pb[3*i];
      ry = pb[3*j+1] - pb[3*i+1];
      rz = pb[3*j+2] - pb[3*i+2];
    }
    rel[tid*3+0] = rx; rel[tid*3+1] = ry; rel[tid*3+2] = rz;
  }
  __syncthreads();

  // --- conv phase B: h1[k][h0..h0+3] = relu(U[j] (+b1) + rel . Wrel) ---
  constexpr int QPK = H / 4;
  for (int qi = tid; qi < 32 * QPK; qi += T) {
    const int k = qi / QPK, h0 = (qi - k * QPK) * 4;
    const int j = snbr[k];
    float4 v = make_float4(0.f, 0.f, 0.f, 0.f);
    if (j >= 0) {
      float4 a = HASX ? *(const float4*)&U[((size_t)b * N + j) * H + h0]
                      : *(const float4*)&b1[h0];
      const float rx = rel[k*3], ry = rel[k*3+1], rz = rel[k*3+2];
      const float4 w0 = *(const float4*)&Wrel[h0];
      const float4 w1 = *(const float4*)&Wrel[H + h0];
      const float4 w2 = *(const float4*)&Wrel[2 * H + h0];
      a.x += rx * w0.x + ry * w1.x + rz * w2.x;
      a.y += rx * w0.y + ry * w1.y + rz * w2.y;
      a.z += rx * w0.z + ry * w1.z + rz * w2.z;
      a.w += rx * w0.w + ry * w1.w + rz * w2.w;
      v = make_float4(fmaxf(a.x, 0.f), fmaxf(a.y, 0.f),
                      fmaxf(a.z, 0.f), fmaxf(a.w, 0.f));
    }
    *(float4*)&h1s[k * H + h0] = v;
  }
  const int cc = tid & 63;
  const int kk = tid >> 6;          // 0..NW-1
  constexpr int CC = C / 64;
  float acc[EPK][CC];
#pragma unroll
  for (int e = 0; e < EPK; e++)
#pragma unroll
    for (int q = 0; q < CC; q++) acc[e][q] = 0.f;
  // --- conv phase C: h2 = h1 @ W2 (W2 staged transposed+padded) ---
  for (int hc = 0; hc < H; hc += HCHUNK) {
    __syncthreads();
    for (int idx = tid; idx < HCHUNK * C; idx += T) {
      const int hh = idx / C, c = idx - hh * C;
      sW2T[c * STR + hh] = W2[(size_t)(hc + hh) * C + c];
    }
    __syncthreads();
    for (int hh0 = 0; hh0 < HCHUNK; hh0 += 4) {
      float4 wv[CC];
#pragma unroll
      for (int q = 0; q < CC; q++)
        wv[q] = *(const float4*)&sW2T[(cc + q * 64) * STR + hh0];
#pragma unroll
      for (int e = 0; e < EPK; e++) {
        const float4 hv = *(const float4*)&h1s[(kk + e * NW) * H + hc + hh0];
#pragma unroll
        for (int q = 0; q < CC; q++) {
          acc[e][q] += hv.x * wv[q].x;
          acc[e][q] += hv.y * wv[q].y;
          acc[e][q] += hv.z * wv[q].z;
          acc[e][q] += hv.w * wv[q].w;
        }
      }
    }
  }
  // --- masked max over k, +b2, relu ---
  float m[CC];
#pragma unroll
  for (int q = 0; q < CC; q++) m[q] = -1e9f;
#pragma unroll
  for (int e = 0; e < EPK; e++) {
    if (snbr[kk + e * NW] >= 0) {
#pragma unroll
      for (int q = 0; q < CC; q++) m[q] = fmaxf(m[q], acc[e][q]);
    }
  }
#pragma unroll
  for (int q = 0; q < CC; q++) sRed[kk * C + cc + q * 64] = m[q];
  __syncthreads();
  if (kk == 0) {
#pragma unroll
    for (int q = 0; q < CC; q++) {
      const int c = cc + q * 64;
      float mm = sRed[c];
#pragma unroll
      for (int w2 = 1; w2 < NW; w2++) mm = fmaxf(mm, sRed[w2 * C + c]);
      const float o = (mm > -5e8f) ? (mm + b2[c]) : -1e9f;
      const float r = fmaxf(o, 0.f);
      if (FOLDMAX) {
        atomicMax((int*)&out[b * C + c], __float_as_int(r));  // r >= 0
      } else {
        out[((size_t)b * N + i) * C + c] = r;
      }
    }
  }
}

// ---------------- stage kernels (distinct names for profiling) --------------
template<int N, int NOUT, int H, int C, bool HASX, int SMSIZE>
__device__ __forceinline__ void stage_fused_impl(
    const float* pos, double rr, int* fi, const float* U, const float* Wrel,
    const float* b1, const float* W2, const float* b2, float* out, char* sm) {
  if (blockIdx.x < NB) {
    fps_body<N, NOUT, 512>(sm, pos + (size_t)blockIdx.x * N * 3, fi, blockIdx.x);
  } else {
    const int row = blockIdx.x - NB;
    const int b = row / N;
    const int i = row - b * N;
    knnconv_body<N, H, C, HASX, false, 512>(sm, pos + (size_t)b * N * 3, b, i,
                                            U, Wrel, b1, W2, b2, out, rr);
  }
}

__global__ __attribute__((amdgpu_waves_per_eu(2, 2))) __launch_bounds__(512, 2)
void stage1_kernel(const float* __restrict__ pos, double rr, int* __restrict__ fi,
                   const float* __restrict__ Wrel, const float* __restrict__ b1,
                   const float* __restrict__ W2, const float* __restrict__ b2,
                   float* __restrict__ out) {
  __shared__ __align__(16) char sm[82944];  // pad >80KB -> 1 blk/CU (fps isolation)
  stage_fused_impl<4096, 2048, 64, 64, false, 82944>(
      pos, rr, fi, nullptr, Wrel, b1, W2, b2, out, sm);
}

__global__ __attribute__((amdgpu_waves_per_eu(2, 2))) __launch_bounds__(512, 2)
void stage2_kernel(const float* __restrict__ pos, double rr, int* __restrict__ fi,
                   const float* __restrict__ U, const float* __restrict__ Wrel,
                   const float* __restrict__ b1, const float* __restrict__ W2,
                   const float* __restrict__ b2, float* __restrict__ out) {
  __shared__ __align__(16) char sm[39440];  // 4 blk/CU
  stage_fused_impl<2048, 512, 128, 128, true, 39440>(
      pos, rr, fi, U, Wrel, b1, W2, b2, out, sm);
}

__global__ __launch_bounds__(512)
void stage3_kernel(const float* __restrict__ pos, double rr,
                   const float* __restrict__ U, const float* __restrict__ Wrel,
                   const float* __restrict__ b1, const float* __restrict__ W2,
                   const float* __restrict__ b2, float* __restrict__ feat) {
  __shared__ __align__(16) char sm[61968];  // 2 blk/CU
  const int b = blockIdx.x / 512;
  const int i = blockIdx.x - b * 512;
  knnconv_body<512, 256, 256, true, true, 512>(sm, pos + (size_t)b * 512 * 3,
                                               b, i, U, Wrel, b1, W2, b2,
                                               feat, rr);
}

// ---------------- fused gather + preproj (U = x[fi] @ W[:CIN] + b) ----------
template<int CIN, int HH>
__global__ __launch_bounds__(HH)
void gp_kernel(const float* __restrict__ X, const float* __restrict__ posPrev,
               const int* __restrict__ fi, int Nprev, int M,
               const float* __restrict__ W, const float* __restrict__ bias,
               float* __restrict__ U, float* __restrict__ posDst) {
  const int row = blockIdx.x;
  const int b = row / M;
  const int tid = threadIdx.x;
  const int j = fi[row];
  __shared__ float sx[CIN];
  if (tid < CIN) sx[tid] = X[((size_t)b * Nprev + j) * CIN + tid];
  if (tid < 3) posDst[(size_t)row * 3 + tid] = posPrev[((size_t)b * Nprev + j) * 3 + tid];
  __syncthreads();
  float a = bias[tid];
  for (int f = 0; f < CIN; f++) a = fmaf(sx[f], W[f * HH + tid], a);
  U[(size_t)row * HH + tid] = a;
}

// ---------------- classifier/defense heads (feat precomputed) ---------------
__global__ __launch_bounds__(256) void head_kernel(
    const float* __restrict__ feat,
    const float* __restrict__ Wc1, const float* __restrict__ bc1,
    const float* __restrict__ Wc2, const float* __restrict__ bc2,
    const float* __restrict__ Wc3, const float* __restrict__ bc3,
    const float* __restrict__ Wd1, const float* __restrict__ bd1,
    const float* __restrict__ Wd2, const float* __restrict__ bd2,
    float* __restrict__ out) {
  const int b = blockIdx.x, tid = threadIdx.x;
  __shared__ float sf[256], sh[256], sh2[256], shd[256], sl[48];
  sf[tid] = feat[b * 256 + tid];
  __syncthreads();
  float a = bc1[tid], ad = bd1[tid];
  for (int f = 0; f < 256; f++) {
    const float fv = sf[f];
    a  = fmaf(fv, Wc1[f * 256 + tid], a);
    ad = fmaf(fv, Wd1[f * 256 + tid], ad);
  }
  sh[tid] = fmaxf(a, 0.f);
  shd[tid] = fmaxf(ad, 0.f);
  __syncthreads();
  float a2 = bc2[tid];
  for (int f = 0; f < 256; f++) a2 = fmaf(sh[f], Wc2[f * 256 + tid], a2);
  sh2[tid] = fmaxf(a2, 0.f);
  __syncthreads();
  if (tid < 40) {
    float l = bc3[tid];
    for (int f = 0; f < 256; f++) l = fmaf(sh2[f], Wc3[f * 40 + tid], l);
    sl[tid] = l;
  }
  if (tid >= 64 && tid < 66) {
    const int q = tid - 64;
    float l = bd2[q];
    for (int f = 0; f < 256; f++) l = fmaf(shd[f], Wd2[f * 2 + q], l);
    sl[40 + q] = l;
  }
  __syncthreads();
  if (tid == 0) {
    float m0 = sl[0];
    for (int q = 1; q < 40; q++) m0 = fmaxf(m0, sl[q]);
    float s = 0.f;
    for (int q = 0; q < 40; q++) s += expf(sl[q] - m0);
    const float ls = logf(s);
    for (int q = 0; q < 40; q++) out[b * 40 + q] = sl[q] - m0 - ls;
    const float m1 = fmaxf(sl[40], sl[41]);
    const float s1 = expf(sl[40] - m1) + expf(sl[41] - m1);
    const float ls1 = logf(s1);
    out[320 + b * 2 + 0] = sl[40] - m1 - ls1;
    out[320 + b * 2 + 1] = sl[41] - m1 - ls1;
  }
}

// ---------------------------------------------------------------------------
extern "C" void kernel_launch(void* const* d_in, const int* in_sizes, int n_in,
                              void* d_out, int out_size, void* d_ws, size_t ws_size,
                              hipStream_t stream) {
  (void)in_sizes; (void)n_in; (void)out_size; (void)ws_size;
  const float* pos = (const float*)d_in[0];
  const float* W1a = (const float*)d_in[1];  const float* b1a = (const float*)d_in[2];
  const float* W1b = (const float*)d_in[3];  const float* b1b = (const float*)d_in[4];
  const float* W2a = (const float*)d_in[5];  const float* b2a = (const float*)d_in[6];
  const float* W2b = (const float*)d_in[7];  const float* b2b = (const float*)d_in[8];
  const float* W3a = (const float*)d_in[9];  const float* b3a = (const float*)d_in[10];
  const float* W3b = (const float*)d_in[11]; const float* b3b = (const float*)d_in[12];
  const float* Wc1 = (const float*)d_in[13]; const float* bc1 = (const float*)d_in[14];
  const float* Wc2 = (const float*)d_in[15]; const float* bc2 = (const float*)d_in[16];
  const float* Wc3 = (const float*)d_in[17]; const float* bc3 = (const float*)d_in[18];
  const float* Wd1 = (const float*)d_in[19]; const float* bd1 = (const float*)d_in[20];
  const float* Wd2 = (const float*)d_in[21]; const float* bd2 = (const float*)d_in[22];
  float* out = (float*)d_out;

  char* w = (char*)d_ws;
  auto alloc = [&](size_t bytes) -> void* {
    void* p = (void*)w;
    w += (bytes + 255) & ~(size_t)255;
    return p;
  };
  int*   fi1  = (int*)  alloc((size_t)NB*2048*4);
  float* x1   = (float*)alloc((size_t)NB*4096*64*4);
  float* pos2 = (float*)alloc((size_t)NB*2048*3*4);
  float* U2   = (float*)alloc((size_t)NB*2048*128*4);
  float* x2   = (float*)alloc((size_t)NB*2048*128*4);
  int*   fi2  = (int*)  alloc((size_t)NB*512*4);
  float* pos3 = (float*)alloc((size_t)NB*512*3*4);
  float* U3   = (float*)alloc((size_t)NB*512*256*4);
  float* feat = (float*)alloc((size_t)NB*256*4);

  // feat = 0 (atomicMax target; all pooled values are >= 0 post-relu)
  hipMemsetAsync(feat, 0, (size_t)NB * 256 * 4, stream);

  // stage 1: {fps1 || knn1+conv1}  (both depend only on pos)
  stage1_kernel<<<NB + NB * 4096, 512, 0, stream>>>(
      pos, 0.2 * 0.2, fi1, W1a, b1a, W1b, b1b, x1);

  // gather1 + preproj2 (U2 = x1[fi1] @ W2a[:64] + b2a)
  gp_kernel<64, 128><<<NB * 2048, 128, 0, stream>>>(
      x1, pos, fi1, 4096, 2048, W2a, b2a, U2, pos2);

  // stage 2: {fps2 || knn2+conv2}
  stage2_kernel<<<NB + NB * 2048, 512, 0, stream>>>(
      pos2, 0.4 * 0.4, fi2, U2, W2a + (size_t)64 * 128, b2a, W2b, b2b, x2);

  // gather2 + preproj3
  gp_kernel<128, 256><<<NB * 512, 256, 0, stream>>>(
      x2, pos2, fi2, 2048, 512, W3a, b3a, U3, pos3);

  // stage 3: knn3+conv3 with fused global max-pool (atomicMax into feat)
  stage3_kernel<<<NB * 512, 512, 0, stream>>>(
      pos3, 1.0, U3, W3a + (size_t)128 * 256, b3a, W3b, b3b, feat);

  // heads
  head_kernel<<<NB, 256, 0, stream>>>(feat, Wc1, bc1, Wc2, bc2, Wc3, bc3,
                                      Wd1, bd1, Wd2, bd2, out);
}